// Round 14
// baseline (363.422 us; speedup 1.0000x reference)
//
#include <hip/hip_runtime.h>
#include <math.h>

constexpr int BB  = 32;
constexpr int SQL = 2048;
constexpr int SKL = 2048;
constexpr int DD  = 64;

using f32x4 = __attribute__((ext_vector_type(4))) float;
using bfrag = __attribute__((ext_vector_type(8))) short;   // 8 bf16 = 4 VGPR
typedef unsigned long long u64;

static __device__ __forceinline__ unsigned short f2bf(float x) {
    unsigned u = __float_as_uint(x);
    u = u + 0x7FFFu + ((u >> 16) & 1u);          // round-nearest-even
    return (unsigned short)(u >> 16);
}
static __device__ __forceinline__ float bf2f(unsigned short h) {
    return __uint_as_float((unsigned)h << 16);
}

// async global->LDS, 16 B per lane (wave-uniform base + lane*16 dest)
static __device__ __forceinline__ void gld16(const void* g, void* l) {
    __builtin_amdgcn_global_load_lds(
        (const __attribute__((address_space(1))) void*)(size_t)g,
        (__attribute__((address_space(3))) void*)(unsigned)(size_t)l,
        16, 0, 0);
}

// ---- prepass: k fp32 -> swizzled bf16 hi/lo records (proven r6/r9/r13).
// Per (b,c): 256 B = [hi 128B][lo 128B]; 16-B groups XOR'd by ((c&7)<<4).
__global__ __launch_bounds__(256) void split_k_swz(
    const float* __restrict__ k, unsigned char* __restrict__ kswz)
{
    const int i0 = blockIdx.x * blockDim.x + threadIdx.x;  // (b,c,g)
    const int g  = i0 & 7;
    const int c  = (i0 >> 3) & 2047;
    const int b  = i0 >> 14;
    const float* kp = k + ((size_t)(b * 2048 + c)) * DD + g * 8;
    bfrag h, lo;
    #pragma unroll
    for (int j = 0; j < 8; ++j) {
        const float x = kp[j];
        const unsigned short hh = f2bf(x);
        h[j]  = (short)hh;
        lo[j] = (short)f2bf(x - bf2f(hh));
    }
    const int sw = (c & 7) << 4;
    unsigned char* rec = kswz + ((size_t)(b * 2048 + c)) * 256;
    *(bfrag*)(rec + ((g * 16) ^ sw))       = h;
    *(bfrag*)(rec + 128 + ((g * 16) ^ sw)) = lo;
}

#define MF(A, B, C) __builtin_amdgcn_mfma_f32_16x16x32_bf16((A), (B), (C), 0, 0, 0)

// ---- main: block = 8 waves = 128 q-rows x 2048 cols; two passes over k.
// Shared k ring (3 x 8KB = 32 cols/step) + mask ring (3 x 16KB), staged by
// gld16 DMA, m201-style counted-vmcnt + barrier pipeline. Pass A: row sums +
// bit-pack mask (regs -> d_ws per 8-step group). Pass B: recompute + store.
template<bool PRE>
__global__ __launch_bounds__(512, 4) void sdpa_v14(
    const float* __restrict__ q, const float* __restrict__ k,
    const int* __restrict__ mask, const unsigned char* __restrict__ kswz,
    u64* __restrict__ bits, float* __restrict__ out)
{
    __shared__ char kring[3 * 8192];
    __shared__ char mring[3 * 16384];

    const int t   = threadIdx.x;
    const int l   = t & 63;
    const int w   = t >> 6;
    const int lr  = l & 15;
    const int lg  = l >> 4;
    const int bid = blockIdx.x;
    const int swz = (bid & 7) * 64 + (bid >> 3);   // bijective XCD chunking
    const int b   = swz >> 4;                      // batch
    const int r0  = (swz & 15) * 128;              // q-row base (128 rows)
    const int R   = w * 16 + lr;                   // row within block
    const size_t rowg = (size_t)b * SQL + (size_t)(r0 + R);
    const int swk   = (lr & 7) << 4;
    const int koff0 = (lg * 16) ^ swk;
    const int koff1 = ((lg + 4) * 16) ^ swk;
    const int moff0 = R * 128 + ((lg ^ (R & 7)) << 4);
    const int moff1 = R * 128 + (((4 | lg) ^ (R & 7)) << 4);

    // ---- q fragments, scale (log2e/8) folded, hi/lo split
    constexpr float QS = 0.18033688011112042f;     // 0.125 * log2(e)
    bfrag qh0, ql0, qh1, ql1;
    {
        const float* qp = q + rowg * DD + lg * 8;
        const f32x4 x0 = *(const f32x4*)qp;
        const f32x4 x1 = *(const f32x4*)(qp + 4);
        const f32x4 y0 = *(const f32x4*)(qp + 32);
        const f32x4 y1 = *(const f32x4*)(qp + 36);
        #pragma unroll
        for (int j = 0; j < 4; ++j) {
            float a = x0[j] * QS, c = x1[j] * QS;
            float d = y0[j] * QS, e = y1[j] * QS;
            unsigned short h;
            h = f2bf(a); qh0[j]     = (short)h; ql0[j]     = (short)f2bf(a - bf2f(h));
            h = f2bf(c); qh0[j + 4] = (short)h; ql0[j + 4] = (short)f2bf(c - bf2f(h));
            h = f2bf(d); qh1[j]     = (short)h; ql1[j]     = (short)f2bf(d - bf2f(h));
            h = f2bf(e); qh1[j + 4] = (short)h; ql1[j + 4] = (short)f2bf(e - bf2f(h));
        }
    }

    const char*  kstg = PRE ? (const char*)kswz + ((size_t)b * SKL) * 256 + t * 16 : nullptr;
    const float* kraw = PRE ? nullptr : k + (size_t)b * SKL * DD;
    // mask DMA source: LDS row = t>>3 (+64 for part B), group permuted by row
    const char* mstgA = (const char*)mask
        + ((size_t)b * SQL + (size_t)(r0 + (t >> 3))) * (SKL * 4)
        + (size_t)(((t & 7) ^ ((t >> 3) & 7)) << 4);
    const char* mstgB = mstgA + (size_t)64 * (SKL * 4);
    u64*  bitsp = PRE ? bits + ((size_t)bid * 512 + t) * 8 : nullptr;
    const int* mdir = mask + rowg * SKL + lg * 4;   // !PRE pass-B direct mask
    float* outp = out + rowg * SKL + lg * 4;

    // !PRE cooperative k-convert constants
    const int cvc   = t >> 4;                       // local col 0..31
    const int cvd   = t & 15;                       // d-quad 0..15
    const int cvrec = cvc * 256 + (((cvd >> 1) * 16) ^ ((cvc & 7) << 4)) + (cvd & 1) * 8;

#define STAGE_B(TT)                                                            \
  do {                                                                         \
    char* _kd = kring + sl * 8192;                                             \
    if constexpr (PRE) {                                                       \
      gld16(kstg + (size_t)(TT) * 8192, _kd + t * 16);                         \
    } else {                                                                   \
      const float* _kp = kraw + (size_t)((TT) * 32 + cvc) * 64 + cvd * 4;      \
      const f32x4 _v = *(const f32x4*)_kp;                                     \
      short4 _hi, _lo;                                                         \
      { unsigned short _t2;                                                    \
        _t2 = f2bf(_v[0]); _hi.x = (short)_t2; _lo.x = (short)f2bf(_v[0] - bf2f(_t2)); \
        _t2 = f2bf(_v[1]); _hi.y = (short)_t2; _lo.y = (short)f2bf(_v[1] - bf2f(_t2)); \
        _t2 = f2bf(_v[2]); _hi.z = (short)_t2; _lo.z = (short)f2bf(_v[2] - bf2f(_t2)); \
        _t2 = f2bf(_v[3]); _hi.w = (short)_t2; _lo.w = (short)f2bf(_v[3] - bf2f(_t2)); } \
      *(short4*)(_kd + cvrec)       = _hi;                                     \
      *(short4*)(_kd + cvrec + 128) = _lo;                                     \
    }                                                                          \
  } while (0)

#define STAGE_A(TT)                                                            \
  do {                                                                         \
    STAGE_B(TT);                                                               \
    char* _md = mring + sl * 16384;                                            \
    gld16(mstgA + (size_t)(TT) * 128, _md + t * 16);                           \
    gld16(mstgB + (size_t)(TT) * 128, _md + 8192 + t * 16);                    \
  } while (0)

#define FRAGS                                                                  \
    const char* _kc = kring + sl * 8192 + lr * 256;                            \
    const bfrag _kh0 = *(const bfrag*)(_kc + koff0);                           \
    const bfrag _kh1 = *(const bfrag*)(_kc + koff1);                           \
    const bfrag _kl0 = *(const bfrag*)(_kc + 128 + koff0);                     \
    const bfrag _kl1 = *(const bfrag*)(_kc + 128 + koff1);                     \
    const bfrag _jh0 = *(const bfrag*)(_kc + 4096 + koff0);                    \
    const bfrag _jh1 = *(const bfrag*)(_kc + 4096 + koff1);                    \
    const bfrag _jl0 = *(const bfrag*)(_kc + 4096 + 128 + koff0);              \
    const bfrag _jl1 = *(const bfrag*)(_kc + 4096 + 128 + koff1);

#define MMAS                                                                   \
    f32x4 _h0 = {0.f,0.f,0.f,0.f}, _x0 = {0.f,0.f,0.f,0.f};                    \
    f32x4 _h1 = {0.f,0.f,0.f,0.f}, _x1 = {0.f,0.f,0.f,0.f};                    \
    _h0 = MF(_kh0, qh0, _h0);  _x0 = MF(_kh0, ql0, _x0);                       \
    _h0 = MF(_kh1, qh1, _h0);  _x0 = MF(_kl0, qh0, _x0);                       \
    _x0 = MF(_kh1, ql1, _x0);  _x0 = MF(_kl1, qh1, _x0);                       \
    _h1 = MF(_jh0, qh0, _h1);  _x1 = MF(_jh0, ql0, _x1);                       \
    _h1 = MF(_jh1, qh1, _h1);  _x1 = MF(_jl0, qh0, _x1);                       \
    _x1 = MF(_jh1, ql1, _x1);  _x1 = MF(_jl1, qh1, _x1);                       \
    const f32x4 _s0 = _h0 + _x0;                                               \
    const f32x4 _s1 = _h1 + _x1;

#define NIB4(M) ((unsigned)((M).x ? 1u:0u) | ((M).y ? 2u:0u) |                 \
                 ((M).z ? 4u:0u) | ((M).w ? 8u:0u))

#define STEP_A(TT, VP, VN, SH, DOSTAGE)                                        \
  do {                                                                         \
    if constexpr (PRE) { asm volatile("s_waitcnt vmcnt(" #VP ")" ::: "memory"); } \
    else { asm volatile("s_waitcnt vmcnt(" #VN ") lgkmcnt(0)" ::: "memory"); } \
    __builtin_amdgcn_sched_barrier(0);                                         \
    __builtin_amdgcn_s_barrier();                                              \
    __builtin_amdgcn_sched_barrier(0);                                         \
    FRAGS                                                                      \
    const char* _mb = mring + sl * 16384;                                      \
    const int4 _m0 = *(const int4*)(_mb + moff0);                              \
    const int4 _m1 = *(const int4*)(_mb + moff1);                              \
    asm volatile("s_waitcnt lgkmcnt(0)" ::: "memory");                         \
    __builtin_amdgcn_sched_barrier(0);                                         \
    MMAS                                                                       \
    const unsigned _n0 = NIB4(_m0);                                            \
    const unsigned _n1 = NIB4(_m1);                                            \
    psum += ((_n0 & 1u) ? exp2f(_s0[0]) : 0.f) + ((_n0 & 2u) ? exp2f(_s0[1]) : 0.f) \
          + ((_n0 & 4u) ? exp2f(_s0[2]) : 0.f) + ((_n0 & 8u) ? exp2f(_s0[3]) : 0.f) \
          + ((_n1 & 1u) ? exp2f(_s1[0]) : 0.f) + ((_n1 & 2u) ? exp2f(_s1[1]) : 0.f) \
          + ((_n1 & 4u) ? exp2f(_s1[2]) : 0.f) + ((_n1 & 8u) ? exp2f(_s1[3]) : 0.f); \
    bv |= ((u64)(_n0 | (_n1 << 4))) << (SH);                                   \
    __builtin_amdgcn_sched_barrier(0);                                         \
    __builtin_amdgcn_s_barrier();                                              \
    __builtin_amdgcn_sched_barrier(0);                                         \
    if (DOSTAGE) { STAGE_A((TT) + 3); }                                        \
    sl = (sl == 2) ? 0 : sl + 1;                                               \
  } while (0)

#define STEP_B(TT, VP, SH, DOSTAGE)                                            \
  do {                                                                         \
    if constexpr (PRE) { asm volatile("s_waitcnt vmcnt(" #VP ")" ::: "memory"); } \
    else { asm volatile("s_waitcnt lgkmcnt(0)" ::: "memory"); }                \
    __builtin_amdgcn_sched_barrier(0);                                         \
    __builtin_amdgcn_s_barrier();                                              \
    __builtin_amdgcn_sched_barrier(0);                                         \
    FRAGS                                                                      \
    asm volatile("s_waitcnt lgkmcnt(0)" ::: "memory");                         \
    __builtin_amdgcn_sched_barrier(0);                                         \
    MMAS                                                                       \
    unsigned _n0, _n1;                                                         \
    if constexpr (PRE) {                                                       \
        _n0 = (unsigned)(bq >> (SH)) & 0xFu;                                   \
        _n1 = (unsigned)(bq >> ((SH) + 4)) & 0xFu;                             \
    } else {                                                                   \
        const int4 _m0 = *(const int4*)(mdir + (TT) * 32);                     \
        const int4 _m1 = *(const int4*)(mdir + (TT) * 32 + 16);                \
        _n0 = NIB4(_m0); _n1 = NIB4(_m1);                                      \
    }                                                                          \
    f32x4 _o0, _o1;                                                            \
    _o0[0] = (_n0 & 1u) ? exp2f(_s0[0]) * rinv : 0.f;                          \
    _o0[1] = (_n0 & 2u) ? exp2f(_s0[1]) * rinv : 0.f;                          \
    _o0[2] = (_n0 & 4u) ? exp2f(_s0[2]) * rinv : 0.f;                          \
    _o0[3] = (_n0 & 8u) ? exp2f(_s0[3]) * rinv : 0.f;                          \
    _o1[0] = (_n1 & 1u) ? exp2f(_s1[0]) * rinv : 0.f;                          \
    _o1[1] = (_n1 & 2u) ? exp2f(_s1[1]) * rinv : 0.f;                          \
    _o1[2] = (_n1 & 4u) ? exp2f(_s1[2]) * rinv : 0.f;                          \
    _o1[3] = (_n1 & 8u) ? exp2f(_s1[3]) * rinv : 0.f;                          \
    *(f32x4*)(outp + (TT) * 32)      = _o0;                                    \
    *(f32x4*)(outp + (TT) * 32 + 16) = _o1;                                    \
    __builtin_amdgcn_sched_barrier(0);                                         \
    __builtin_amdgcn_s_barrier();                                              \
    __builtin_amdgcn_sched_barrier(0);                                         \
    if (DOSTAGE) { STAGE_B((TT) + 3); }                                        \
    sl = (sl == 2) ? 0 : sl + 1;                                               \
  } while (0)

    // =================== PASS A ===================
    int sl;
    float psum = 0.f;
    u64 bv = 0;
    sl = 0; STAGE_A(0);
    sl = 1; STAGE_A(1);
    sl = 2; STAGE_A(2);
    sl = 0;

    for (int jg = 0; jg < 7; ++jg) {       // groups 0..6: steps 0..55
        const int T0 = jg * 8;
        bv = 0;
        STEP_A(T0 + 0, 6, 4, 0,  1);
        STEP_A(T0 + 1, 6, 4, 8,  1);
        STEP_A(T0 + 2, 6, 4, 16, 1);
        STEP_A(T0 + 3, 6, 4, 24, 1);
        STEP_A(T0 + 4, 6, 4, 32, 1);
        STEP_A(T0 + 5, 6, 4, 40, 1);
        STEP_A(T0 + 6, 6, 4, 48, 1);
        STEP_A(T0 + 7, 6, 4, 56, 1);
        if constexpr (PRE) bitsp[jg] = bv;
    }
    bv = 0;                                 // group 7 peeled: steps 56..63
    STEP_A(56, 6, 4, 0,  1);
    STEP_A(57, 6, 4, 8,  1);
    STEP_A(58, 6, 4, 16, 1);
    STEP_A(59, 6, 4, 24, 1);
    STEP_A(60, 6, 4, 32, 1);
    STEP_A(61, 6, 4, 40, 0);
    STEP_A(62, 3, 2, 48, 0);
    STEP_A(63, 0, 0, 56, 0);
    if constexpr (PRE) bitsp[7] = bv;

    // ---- row sums: lanes {l, l^16, l^32, l^48} share each q-row
    psum += __shfl_xor(psum, 16, 64);
    psum += __shfl_xor(psum, 32, 64);
    const float rinv = 1.0f / psum;

    // =================== PASS B ===================
    u64 bq = 0, bvn = 0;
    if constexpr (PRE) bq = bitsp[0];
    sl = 0; STAGE_B(0);
    sl = 1; STAGE_B(1);
    sl = 2; STAGE_B(2);
    sl = 0;

    // group 0 peeled (ledger warm-up)
    STEP_B(0, 2, 0, 1);
    if constexpr (PRE) bvn = bitsp[1];
    STEP_B(1, 4, 8,  1);
    STEP_B(2, 6, 16, 1);
    STEP_B(3, 6, 24, 1);
    STEP_B(4, 6, 32, 1);
    STEP_B(5, 6, 40, 1);
    STEP_B(6, 6, 48, 1);
    STEP_B(7, 6, 56, 1);
    bq = bvn;
    for (int jg = 1; jg < 7; ++jg) {       // groups 1..6: steps 8..55
        const int T0 = jg * 8;
        STEP_B(T0 + 0, 6, 0, 1);
        if constexpr (PRE) bvn = bitsp[jg + 1];
        STEP_B(T0 + 1, 6, 8,  1);
        STEP_B(T0 + 2, 6, 16, 1);
        STEP_B(T0 + 3, 6, 24, 1);
        STEP_B(T0 + 4, 6, 32, 1);
        STEP_B(T0 + 5, 6, 40, 1);
        STEP_B(T0 + 6, 6, 48, 1);
        STEP_B(T0 + 7, 6, 56, 1);
        bq = bvn;
    }
    // group 7 peeled: steps 56..63
    STEP_B(56, 6, 0,  1);
    STEP_B(57, 6, 8,  1);
    STEP_B(58, 6, 16, 1);
    STEP_B(59, 6, 24, 1);
    STEP_B(60, 6, 32, 1);
    STEP_B(61, 6, 40, 0);
    STEP_B(62, 5, 48, 0);
    STEP_B(63, 4, 56, 0);

#undef STEP_B
#undef STEP_A
#undef NIB4
#undef MMAS
#undef FRAGS
#undef STAGE_A
#undef STAGE_B
}

extern "C" void kernel_launch(void* const* d_in, const int* in_sizes, int n_in,
                              void* d_out, int out_size, void* d_ws, size_t ws_size,
                              hipStream_t stream) {
    const float* q    = (const float*)d_in[0];
    const float* k    = (const float*)d_in[1];
    const int*   mask = (const int*)d_in[2];
    float*       out  = (float*)d_out;

    const size_t KS_B   = (size_t)BB * SKL * 256;          // 16.78 MB swizzled k
    const size_t BITS_B = (size_t)512 * 512 * 8 * 8;       // 16.78 MB bit scratch

    if (ws_size >= KS_B + BITS_B) {
        unsigned char* ksp = (unsigned char*)d_ws;
        u64* bitsp = (u64*)((char*)d_ws + KS_B);
        split_k_swz<<<2048, 256, 0, stream>>>(k, ksp);
        sdpa_v14<true><<<512, 512, 0, stream>>>(q, k, mask, ksp, bitsp, out);
    } else {
        sdpa_v14<false><<<512, 512, 0, stream>>>(q, k, mask, nullptr, nullptr, out);
    }
}

// Round 15
// 359.358 us; speedup vs baseline: 1.0113x; 1.0113x over previous
//
#include <hip/hip_runtime.h>
#include <math.h>

constexpr int BB  = 32;
constexpr int SQL = 2048;
constexpr int SKL = 2048;
constexpr int DD  = 64;

using f32x4 = __attribute__((ext_vector_type(4))) float;
using bfrag = __attribute__((ext_vector_type(8))) short;   // 8 bf16 = 4 VGPR
typedef unsigned long long u64;

static __device__ __forceinline__ unsigned short f2bf(float x) {
    unsigned u = __float_as_uint(x);
    u = u + 0x7FFFu + ((u >> 16) & 1u);          // round-nearest-even
    return (unsigned short)(u >> 16);
}
static __device__ __forceinline__ float bf2f(unsigned short h) {
    return __uint_as_float((unsigned)h << 16);
}

// async global->LDS, 16 B per lane (wave-uniform base + lane*16 dest)
static __device__ __forceinline__ void gld16(const void* g, void* l) {
    __builtin_amdgcn_global_load_lds(
        (const __attribute__((address_space(1))) void*)(size_t)g,
        (__attribute__((address_space(3))) void*)(unsigned)(size_t)l,
        16, 0, 0);
}

// ---- prepass: k fp32 -> swizzled bf16 hi/lo records (proven r6/r9/r13).
// Per (b,c): 256 B = [hi 128B][lo 128B]; 16-B groups XOR'd by ((c&7)<<4).
__global__ __launch_bounds__(256) void split_k_swz(
    const float* __restrict__ k, unsigned char* __restrict__ kswz)
{
    const int i0 = blockIdx.x * blockDim.x + threadIdx.x;  // (b,c,g)
    const int g  = i0 & 7;
    const int c  = (i0 >> 3) & 2047;
    const int b  = i0 >> 14;
    const float* kp = k + ((size_t)(b * 2048 + c)) * DD + g * 8;
    bfrag h, lo;
    #pragma unroll
    for (int j = 0; j < 8; ++j) {
        const float x = kp[j];
        const unsigned short hh = f2bf(x);
        h[j]  = (short)hh;
        lo[j] = (short)f2bf(x - bf2f(hh));
    }
    const int sw = (c & 7) << 4;
    unsigned char* rec = kswz + ((size_t)(b * 2048 + c)) * 256;
    *(bfrag*)(rec + ((g * 16) ^ sw))       = h;
    *(bfrag*)(rec + 128 + ((g * 16) ^ sw)) = lo;
}

#define MF(A, B, C) __builtin_amdgcn_mfma_f32_16x16x32_bf16((A), (B), (C), 0, 0, 0)
#define WAITV(N) asm volatile("s_waitcnt vmcnt(" #N ")" ::: "memory")
#define WAITL    asm volatile("s_waitcnt lgkmcnt(0)" ::: "memory")
#define SBAR     __builtin_amdgcn_s_barrier()
#define SCHED    __builtin_amdgcn_sched_barrier(0)
#define ADV      sl = (sl == 2) ? 0 : sl + 1

// ---- main: block = 8 waves = 128 q-rows x 2048 cols; two passes over k.
// Shared k ring (3 x 8KB = 32 cols/step) staged by 1 gld16/thread/step,
// exact counted-vmcnt ledgers. Mask: direct per-lane int4 global loads,
// register-prefetched 2 steps ahead (NO mask LDS -> no bank conflicts).
// Pass A: row sums + bit-pack mask into LDS. Pass B: recompute + store.
template<bool PRE>
__global__ __launch_bounds__(512, 4) void sdpa_v15(
    const float* __restrict__ q, const float* __restrict__ k,
    const int* __restrict__ mask, const unsigned char* __restrict__ kswz,
    float* __restrict__ out)
{
    __shared__ char kring[3 * 8192];
    __shared__ u64  bitlds[512][8];

    const int t   = threadIdx.x;
    const int l   = t & 63;
    const int w   = t >> 6;
    const int lr  = l & 15;
    const int lg  = l >> 4;
    const int bid = blockIdx.x;
    const int swz = (bid & 7) * 64 + (bid >> 3);   // bijective XCD chunking
    const int b   = swz >> 4;                      // batch
    const int r0  = (swz & 15) * 128;              // q-row base (128 rows)
    const int R   = w * 16 + lr;                   // row within block
    const size_t rowg = (size_t)b * SQL + (size_t)(r0 + R);
    const int swk   = (lr & 7) << 4;
    const int koff0 = (lg * 16) ^ swk;
    const int koff1 = ((lg + 4) * 16) ^ swk;

    // ---- q fragments, scale (log2e/8) folded, hi/lo split
    constexpr float QS = 0.18033688011112042f;     // 0.125 * log2(e)
    bfrag qh0, ql0, qh1, ql1;
    {
        const float* qp = q + rowg * DD + lg * 8;
        const f32x4 x0 = *(const f32x4*)qp;
        const f32x4 x1 = *(const f32x4*)(qp + 4);
        const f32x4 y0 = *(const f32x4*)(qp + 32);
        const f32x4 y1 = *(const f32x4*)(qp + 36);
        #pragma unroll
        for (int j = 0; j < 4; ++j) {
            float a = x0[j] * QS, c = x1[j] * QS;
            float d = y0[j] * QS, e = y1[j] * QS;
            unsigned short h;
            h = f2bf(a); qh0[j]     = (short)h; ql0[j]     = (short)f2bf(a - bf2f(h));
            h = f2bf(c); qh0[j + 4] = (short)h; ql0[j + 4] = (short)f2bf(c - bf2f(h));
            h = f2bf(d); qh1[j]     = (short)h; ql1[j]     = (short)f2bf(d - bf2f(h));
            h = f2bf(e); qh1[j + 4] = (short)h; ql1[j + 4] = (short)f2bf(e - bf2f(h));
        }
    }
    SCHED;                                         // pin q loads before stages

    const char*  kstg = PRE ? (const char*)kswz + (size_t)b * SKL * 256 + t * 16 : nullptr;
    const float* kraw = PRE ? nullptr : k + (size_t)b * SKL * DD;
    const int*   mdir = mask + rowg * SKL + lg * 4;
    float*       outp = out + rowg * SKL + lg * 4;

    // !PRE cooperative k-convert constants
    const int cvc   = t >> 4;
    const int cvd   = t & 15;
    const int cvrec = cvc * 256 + (((cvd >> 1) * 16) ^ ((cvc & 7) << 4)) + (cvd & 1) * 8;

#define STAGE(TT)                                                              \
  do {                                                                         \
    char* _kd = kring + sl * 8192;                                             \
    if constexpr (PRE) {                                                       \
      gld16(kstg + (size_t)(TT) * 8192, _kd + t * 16);                         \
    } else {                                                                   \
      const float* _kp = kraw + (size_t)((TT) * 32 + cvc) * 64 + cvd * 4;      \
      const f32x4 _v = *(const f32x4*)_kp;                                     \
      short4 _hi, _lo;                                                         \
      { unsigned short _t2;                                                    \
        _t2 = f2bf(_v[0]); _hi.x = (short)_t2; _lo.x = (short)f2bf(_v[0] - bf2f(_t2)); \
        _t2 = f2bf(_v[1]); _hi.y = (short)_t2; _lo.y = (short)f2bf(_v[1] - bf2f(_t2)); \
        _t2 = f2bf(_v[2]); _hi.z = (short)_t2; _lo.z = (short)f2bf(_v[2] - bf2f(_t2)); \
        _t2 = f2bf(_v[3]); _hi.w = (short)_t2; _lo.w = (short)f2bf(_v[3] - bf2f(_t2)); } \
      *(short4*)(_kd + cvrec)       = _hi;                                     \
      *(short4*)(_kd + cvrec + 128) = _lo;                                     \
    }                                                                          \
  } while (0)

#define FRAGS                                                                  \
    const char* _kc = kring + sl * 8192 + lr * 256;                            \
    const bfrag _kh0 = *(const bfrag*)(_kc + koff0);                           \
    const bfrag _kh1 = *(const bfrag*)(_kc + koff1);                           \
    const bfrag _kl0 = *(const bfrag*)(_kc + 128 + koff0);                     \
    const bfrag _kl1 = *(const bfrag*)(_kc + 128 + koff1);                     \
    const bfrag _jh0 = *(const bfrag*)(_kc + 4096 + koff0);                    \
    const bfrag _jh1 = *(const bfrag*)(_kc + 4096 + koff1);                    \
    const bfrag _jl0 = *(const bfrag*)(_kc + 4096 + 128 + koff0);              \
    const bfrag _jl1 = *(const bfrag*)(_kc + 4096 + 128 + koff1);

#define MMAS                                                                   \
    f32x4 _h0 = {0.f,0.f,0.f,0.f}, _x0 = {0.f,0.f,0.f,0.f};                    \
    f32x4 _h1 = {0.f,0.f,0.f,0.f}, _x1 = {0.f,0.f,0.f,0.f};                    \
    _h0 = MF(_kh0, qh0, _h0);  _x0 = MF(_kh0, ql0, _x0);                       \
    _h0 = MF(_kh1, qh1, _h0);  _x0 = MF(_kl0, qh0, _x0);                       \
    _x0 = MF(_kh1, ql1, _x0);  _x0 = MF(_kl1, qh1, _x0);                       \
    _h1 = MF(_jh0, qh0, _h1);  _x1 = MF(_jh0, ql0, _x1);                       \
    _h1 = MF(_jh1, qh1, _h1);  _x1 = MF(_jl0, qh0, _x1);                       \
    _x1 = MF(_jh1, ql1, _x1);  _x1 = MF(_jl1, qh1, _x1);                       \
    const f32x4 _s0 = _h0 + _x0;                                               \
    const f32x4 _s1 = _h1 + _x1;

#define NIB4(M) ((unsigned)((M).x ? 1u:0u) | ((M).y ? 2u:0u) |                 \
                 ((M).z ? 4u:0u) | ((M).w ? 8u:0u))

#define STEP_A(TT, VMC, M0, M1, SH, DOSTAGE, DOMASK)                           \
  do {                                                                         \
    if constexpr (PRE) { WAITV(VMC); }                                         \
    else { asm volatile("s_waitcnt vmcnt(0) lgkmcnt(0)" ::: "memory"); }       \
    SCHED; SBAR; SCHED;                                                        \
    FRAGS                                                                      \
    WAITL; SCHED;                                                              \
    MMAS                                                                       \
    const unsigned _n0 = NIB4(M0);                                             \
    const unsigned _n1 = NIB4(M1);                                             \
    psum += ((_n0 & 1u) ? exp2f(_s0[0]) : 0.f) + ((_n0 & 2u) ? exp2f(_s0[1]) : 0.f) \
          + ((_n0 & 4u) ? exp2f(_s0[2]) : 0.f) + ((_n0 & 8u) ? exp2f(_s0[3]) : 0.f) \
          + ((_n1 & 1u) ? exp2f(_s1[0]) : 0.f) + ((_n1 & 2u) ? exp2f(_s1[1]) : 0.f) \
          + ((_n1 & 4u) ? exp2f(_s1[2]) : 0.f) + ((_n1 & 8u) ? exp2f(_s1[3]) : 0.f); \
    bv |= ((u64)(_n0 | (_n1 << 4))) << (SH);                                   \
    SCHED; SBAR; SCHED;                                                        \
    if (DOSTAGE) { STAGE((TT) + 3); }                                          \
    if (DOMASK) {                                                              \
        M0 = *(const int4*)(mdir + ((TT) + 2) * 32);                           \
        M1 = *(const int4*)(mdir + ((TT) + 2) * 32 + 16);                      \
    }                                                                          \
    ADV;                                                                       \
  } while (0)

#define STEP_B(TT, VMC, SH, DOSTAGE)                                           \
  do {                                                                         \
    if constexpr (PRE) { WAITV(VMC); }                                         \
    else { asm volatile("s_waitcnt vmcnt(0) lgkmcnt(0)" ::: "memory"); }       \
    SCHED; SBAR; SCHED;                                                        \
    FRAGS                                                                      \
    WAITL; SCHED;                                                              \
    MMAS                                                                       \
    const unsigned _n0 = (unsigned)(bq >> (SH)) & 0xFu;                        \
    const unsigned _n1 = (unsigned)(bq >> ((SH) + 4)) & 0xFu;                  \
    f32x4 _o0, _o1;                                                            \
    _o0[0] = (_n0 & 1u) ? exp2f(_s0[0]) * rinv : 0.f;                          \
    _o0[1] = (_n0 & 2u) ? exp2f(_s0[1]) * rinv : 0.f;                          \
    _o0[2] = (_n0 & 4u) ? exp2f(_s0[2]) * rinv : 0.f;                          \
    _o0[3] = (_n0 & 8u) ? exp2f(_s0[3]) * rinv : 0.f;                          \
    _o1[0] = (_n1 & 1u) ? exp2f(_s1[0]) * rinv : 0.f;                          \
    _o1[1] = (_n1 & 2u) ? exp2f(_s1[1]) * rinv : 0.f;                          \
    _o1[2] = (_n1 & 4u) ? exp2f(_s1[2]) * rinv : 0.f;                          \
    _o1[3] = (_n1 & 8u) ? exp2f(_s1[3]) * rinv : 0.f;                          \
    *(f32x4*)(outp + (TT) * 32)      = _o0;                                    \
    *(f32x4*)(outp + (TT) * 32 + 16) = _o1;                                    \
    SCHED; SBAR; SCHED;                                                        \
    if (DOSTAGE) { STAGE((TT) + 3); }                                          \
    ADV;                                                                       \
  } while (0)

    // =================== PASS A ===================
    int sl = 0;
    float psum = 0.f;
    u64 bv = 0;
    STAGE(0); ADV;                    // slot 0
    STAGE(1); ADV;                    // slot 1
    STAGE(2); ADV;                    // slot 2 -> sl back to 0
    int4 me0 = *(const int4*)(mdir);
    int4 me1 = *(const int4*)(mdir + 16);       // m(0)
    int4 mo0 = *(const int4*)(mdir + 32);
    int4 mo1 = *(const int4*)(mdir + 48);       // m(1)

    // group 0 (steps 0..7); ledger: [2,3,3,3,3,3,3,3]
    bv = 0;
    STEP_A(0, 2, me0, me1, 0,  1, 1);
    STEP_A(1, 3, mo0, mo1, 8,  1, 1);
    STEP_A(2, 3, me0, me1, 16, 1, 1);
    STEP_A(3, 3, mo0, mo1, 24, 1, 1);
    STEP_A(4, 3, me0, me1, 32, 1, 1);
    STEP_A(5, 3, mo0, mo1, 40, 1, 1);
    STEP_A(6, 3, me0, me1, 48, 1, 1);
    STEP_A(7, 3, mo0, mo1, 56, 1, 1);
    bitlds[t][0] = bv;

    for (int jg = 1; jg < 7; ++jg) {  // groups 1..6 (steps 8..55), uniform
        const int T0 = jg * 8;
        bv = 0;
        STEP_A(T0 + 0, 3, me0, me1, 0,  1, 1);
        STEP_A(T0 + 1, 3, mo0, mo1, 8,  1, 1);
        STEP_A(T0 + 2, 3, me0, me1, 16, 1, 1);
        STEP_A(T0 + 3, 3, mo0, mo1, 24, 1, 1);
        STEP_A(T0 + 4, 3, me0, me1, 32, 1, 1);
        STEP_A(T0 + 5, 3, mo0, mo1, 40, 1, 1);
        STEP_A(T0 + 6, 3, me0, me1, 48, 1, 1);
        STEP_A(T0 + 7, 3, mo0, mo1, 56, 1, 1);
        bitlds[t][jg] = bv;
    }

    // group 7 (steps 56..63); stages end at T=60, mask loads at T=61
    bv = 0;
    STEP_A(56, 3, me0, me1, 0,  1, 1);
    STEP_A(57, 3, mo0, mo1, 8,  1, 1);
    STEP_A(58, 3, me0, me1, 16, 1, 1);
    STEP_A(59, 3, mo0, mo1, 24, 1, 1);
    STEP_A(60, 3, me0, me1, 32, 1, 1);
    STEP_A(61, 3, mo0, mo1, 40, 0, 1);
    STEP_A(62, 2, me0, me1, 48, 0, 0);
    STEP_A(63, 0, mo0, mo1, 56, 0, 0);
    bitlds[t][7] = bv;

    // ---- row sums: lanes {l, l^16, l^32, l^48} share each q-row (in-wave)
    psum += __shfl_xor(psum, 16, 64);
    psum += __shfl_xor(psum, 32, 64);
    const float rinv = 1.0f / psum;

    // =================== PASS B ===================
    // (step 63's final barrier guarantees all kring reads complete)
    u64 bq = bitlds[t][0];
    STAGE(0); ADV;
    STAGE(1); ADV;
    STAGE(2); ADV;                    // sl returns to pre-stage value

    // group 0; ledger: [2,4,6,6,6,6,6,6]  (2 stores/step counted)
    STEP_B(0, 2, 0,  1);
    STEP_B(1, 4, 8,  1);
    STEP_B(2, 6, 16, 1);
    STEP_B(3, 6, 24, 1);
    STEP_B(4, 6, 32, 1);
    STEP_B(5, 6, 40, 1);
    STEP_B(6, 6, 48, 1);
    STEP_B(7, 6, 56, 1);

    for (int jg = 1; jg < 7; ++jg) {  // groups 1..6, uniform vmcnt(6)
        bq = bitlds[t][jg];
        const int T0 = jg * 8;
        STEP_B(T0 + 0, 6, 0,  1);
        STEP_B(T0 + 1, 6, 8,  1);
        STEP_B(T0 + 2, 6, 16, 1);
        STEP_B(T0 + 3, 6, 24, 1);
        STEP_B(T0 + 4, 6, 32, 1);
        STEP_B(T0 + 5, 6, 40, 1);
        STEP_B(T0 + 6, 6, 48, 1);
        STEP_B(T0 + 7, 6, 56, 1);
    }

    // group 7; stages end at T=60; tails vmcnt 5, 4
    bq = bitlds[t][7];
    STEP_B(56, 6, 0,  1);
    STEP_B(57, 6, 8,  1);
    STEP_B(58, 6, 16, 1);
    STEP_B(59, 6, 24, 1);
    STEP_B(60, 6, 32, 1);
    STEP_B(61, 6, 40, 0);
    STEP_B(62, 5, 48, 0);
    STEP_B(63, 4, 56, 0);

#undef STEP_B
#undef STEP_A
#undef NIB4
#undef MMAS
#undef FRAGS
#undef STAGE
}

extern "C" void kernel_launch(void* const* d_in, const int* in_sizes, int n_in,
                              void* d_out, int out_size, void* d_ws, size_t ws_size,
                              hipStream_t stream) {
    const float* q    = (const float*)d_in[0];
    const float* k    = (const float*)d_in[1];
    const int*   mask = (const int*)d_in[2];
    float*       out  = (float*)d_out;

    const size_t KS_B = (size_t)BB * SKL * 256;   // 16.78 MB swizzled k

    if (ws_size >= KS_B) {
        unsigned char* ksp = (unsigned char*)d_ws;
        split_k_swz<<<2048, 256, 0, stream>>>(k, ksp);
        sdpa_v15<true><<<512, 512, 0, stream>>>(q, k, mask, ksp, out);
    } else {
        sdpa_v15<false><<<512, 512, 0, stream>>>(q, k, mask, nullptr, out);
    }
}

// Round 16
// 310.368 us; speedup vs baseline: 1.1709x; 1.1578x over previous
//
#include <hip/hip_runtime.h>
#include <math.h>

constexpr int BB  = 32;
constexpr int SQL = 2048;
constexpr int SKL = 2048;
constexpr int DD  = 64;

using f32x4 = __attribute__((ext_vector_type(4))) float;
using bfrag = __attribute__((ext_vector_type(8))) short;   // 8 bf16 = 4 VGPR
typedef unsigned long long u64;

static __device__ __forceinline__ unsigned short f2bf(float x) {
    unsigned u = __float_as_uint(x);
    u = u + 0x7FFFu + ((u >> 16) & 1u);          // round-nearest-even
    return (unsigned short)(u >> 16);
}
static __device__ __forceinline__ float bf2f(unsigned short h) {
    return __uint_as_float((unsigned)h << 16);
}

// async global->LDS, 16 B per lane (wave-uniform base + lane*16 dest)
static __device__ __forceinline__ void gld16(const void* g, void* l) {
    __builtin_amdgcn_global_load_lds(
        (const __attribute__((address_space(1))) void*)(size_t)g,
        (__attribute__((address_space(3))) void*)(unsigned)(size_t)l,
        16, 0, 0);
}

// ---- prepass: k fp32 -> swizzled bf16 hi/lo records (proven r6/r9/r13).
// Per (b,c): 256 B = [hi 128B][lo 128B]; 16-B groups XOR'd by ((c&7)<<4).
__global__ __launch_bounds__(256) void split_k_swz(
    const float* __restrict__ k, unsigned char* __restrict__ kswz)
{
    const int i0 = blockIdx.x * blockDim.x + threadIdx.x;  // (b,c,g)
    const int g  = i0 & 7;
    const int c  = (i0 >> 3) & 2047;
    const int b  = i0 >> 14;
    const float* kp = k + ((size_t)(b * 2048 + c)) * DD + g * 8;
    bfrag h, lo;
    #pragma unroll
    for (int j = 0; j < 8; ++j) {
        const float x = kp[j];
        const unsigned short hh = f2bf(x);
        h[j]  = (short)hh;
        lo[j] = (short)f2bf(x - bf2f(hh));
    }
    const int sw = (c & 7) << 4;
    unsigned char* rec = kswz + ((size_t)(b * 2048 + c)) * 256;
    *(bfrag*)(rec + ((g * 16) ^ sw))       = h;
    *(bfrag*)(rec + 128 + ((g * 16) ^ sw)) = lo;
}

#define MF(A, B, C) __builtin_amdgcn_mfma_f32_16x16x32_bf16((A), (B), (C), 0, 0, 0)
#define NIB4(M) ((unsigned)((M).x ? 1u:0u) | ((M).y ? 2u:0u) |                 \
                 ((M).z ? 4u:0u) | ((M).w ? 8u:0u))

// ---- main (r13 skeleton, single-pass, + fused mask stream):
// block = 8 waves = 32 q-rows x 2048 cols; wave w owns 256 cols, computes
// TWO 16-row groups per k-tile sharing k fragments. k fed by gld16 DMA into
// a DEPTH-3 LDS ring; mask fed by direct per-lane int4 loads prefetched
// 3 tiles ahead in 3 static register sets. Per-iter VMEM group = {4 k + 2
// mask}; vmcnt(12) = two newer groups in flight ensures current group done.
template<bool PRE>
__global__ __launch_bounds__(512, 2) void sdpa_v16(
    const float* __restrict__ q, const float* __restrict__ k,
    const int* __restrict__ mask, const unsigned char* __restrict__ kswz,
    float* __restrict__ out)
{
    __shared__ char pool[8 * 12288 + 1024];   // 8 waves x 3 k-bufs + s_red

    const int t   = threadIdx.x;
    const int l   = t & 63;
    const int w   = t >> 6;
    const int lr  = l & 15;
    const int lg  = l >> 4;
    const int bid = blockIdx.x;
    const int swz = (bid & 7) * 256 + (bid >> 3);   // bijective XCD chunking
    const int b   = swz >> 6;                       // batch
    const int r0  = (swz & 63) * 32;                // q-row base (32 rows)
    const int c0  = w * 256;                        // wave's col base
    const size_t row0 = (size_t)b * SQL + (size_t)(r0 + lr);        // g0 row
    const size_t row1 = row0 + 16;                                  // g1 row
    const int swk = (lr & 7) << 4;                  // k LDS swizzle key

    char* kseg = pool + w * 12288;
    const char*  ksrc = PRE ? (const char*)(kswz + ((size_t)b * SKL + c0) * 256) : nullptr;
    const float* kraw = PRE ? nullptr : k + (size_t)b * SKL * DD;
    const int*   mr0  = mask + row0 * SKL + c0 + lg * 4;
    const int*   mr1  = mask + row1 * SKL + c0 + lg * 4;

#define STAGE(T)                                                               \
    do {                                                                       \
        char* _kd = kseg + ((T) % 3) * 4096;                                   \
        if constexpr (PRE) {                                                   \
            const char* _ks = ksrc + (size_t)(T) * 4096;                       \
            gld16(_ks + l * 16,        _kd + l * 16);                          \
            gld16(_ks + 1024 + l * 16, _kd + 1024 + l * 16);                   \
            gld16(_ks + 2048 + l * 16, _kd + 2048 + l * 16);                   \
            gld16(_ks + 3072 + l * 16, _kd + 3072 + l * 16);                   \
        } else {                                                               \
            const float* _kc = kraw + (size_t)(c0 + (T) * 16 + lr) * DD;       \
            const f32x4 _a0 = *(const f32x4*)(_kc + lg * 8);                   \
            const f32x4 _a1 = *(const f32x4*)(_kc + lg * 8 + 4);               \
            const f32x4 _b0 = *(const f32x4*)(_kc + (lg + 4) * 8);             \
            const f32x4 _b1 = *(const f32x4*)(_kc + (lg + 4) * 8 + 4);         \
            bfrag _h, _o;                                                      \
            _Pragma("unroll")                                                  \
            for (int _j = 0; _j < 4; ++_j) {                                   \
                unsigned short _t2;                                            \
                _t2 = f2bf(_a0[_j]); _h[_j]   = (short)_t2;                    \
                _o[_j]   = (short)f2bf(_a0[_j] - bf2f(_t2));                   \
                _t2 = f2bf(_a1[_j]); _h[_j+4] = (short)_t2;                    \
                _o[_j+4] = (short)f2bf(_a1[_j] - bf2f(_t2));                   \
            }                                                                  \
            char* _rec = _kd + lr * 256;                                       \
            *(bfrag*)(_rec + ((lg * 16) ^ swk))       = _h;                    \
            *(bfrag*)(_rec + 128 + ((lg * 16) ^ swk)) = _o;                    \
            _Pragma("unroll")                                                  \
            for (int _j = 0; _j < 4; ++_j) {                                   \
                unsigned short _t2;                                            \
                _t2 = f2bf(_b0[_j]); _h[_j]   = (short)_t2;                    \
                _o[_j]   = (short)f2bf(_b0[_j] - bf2f(_t2));                   \
                _t2 = f2bf(_b1[_j]); _h[_j+4] = (short)_t2;                    \
                _o[_j+4] = (short)f2bf(_b1[_j] - bf2f(_t2));                   \
            }                                                                  \
            *(bfrag*)(_rec + (((lg + 4) * 16) ^ swk))       = _h;              \
            *(bfrag*)(_rec + 128 + (((lg + 4) * 16) ^ swk)) = _o;              \
        }                                                                      \
    } while (0)

    // ---- prologue: stage groups 0..2 (k DMA + mask int4 per group)
    int4 mA0, mB0, mA1, mB1, mA2, mB2;       // 3 static mask sets (24 VGPR)
    STAGE(0);
    mA0 = *(const int4*)(mr0);      mB0 = *(const int4*)(mr1);
    STAGE(1);
    mA1 = *(const int4*)(mr0 + 16); mB1 = *(const int4*)(mr1 + 16);
    STAGE(2);
    mA2 = *(const int4*)(mr0 + 32); mB2 = *(const int4*)(mr1 + 32);

    // ---- q fragments for both row groups, scale (log2e/8) folded, hi/lo
    constexpr float QS = 0.18033688011112042f;      // 0.125 * log2(e)
    bfrag qh0a, ql0a, qh1a, ql1a;                   // group 0 (rows r0..+15)
    bfrag qh0b, ql0b, qh1b, ql1b;                   // group 1 (rows +16..31)
#define LOADQ(ROW, H0, L0, H1, L1)                                             \
    do {                                                                       \
        const float* _qp = q + (ROW) * DD + lg * 8;                            \
        const f32x4 _x0 = *(const f32x4*)_qp;                                  \
        const f32x4 _x1 = *(const f32x4*)(_qp + 4);                            \
        const f32x4 _y0 = *(const f32x4*)(_qp + 32);                           \
        const f32x4 _y1 = *(const f32x4*)(_qp + 36);                           \
        _Pragma("unroll")                                                      \
        for (int _j = 0; _j < 4; ++_j) {                                       \
            float _a = _x0[_j] * QS, _c = _x1[_j] * QS;                        \
            float _d = _y0[_j] * QS, _e = _y1[_j] * QS;                        \
            unsigned short _h;                                                 \
            _h = f2bf(_a); H0[_j]   = (short)_h; L0[_j]   = (short)f2bf(_a - bf2f(_h)); \
            _h = f2bf(_c); H0[_j+4] = (short)_h; L0[_j+4] = (short)f2bf(_c - bf2f(_h)); \
            _h = f2bf(_d); H1[_j]   = (short)_h; L1[_j]   = (short)f2bf(_d - bf2f(_h)); \
            _h = f2bf(_e); H1[_j+4] = (short)_h; L1[_j+4] = (short)f2bf(_e - bf2f(_h)); \
        }                                                                      \
    } while (0)
    LOADQ(row0, qh0a, ql0a, qh1a, ql1a);
    LOADQ(row1, qh0b, ql0b, qh1b, ql1b);
#undef LOADQ

    unsigned sc[64];                  // packed bf16 exp: [tile][g][pair]
    float psum0 = 0.f, psum1 = 0.f;

#define ITER(T, VMC, MA, MB, DOPF)                                             \
    do {                                                                       \
        if constexpr (PRE)                                                     \
            asm volatile("s_waitcnt vmcnt(" #VMC ")" ::: "memory");            \
        const char* _c = kseg + ((T) % 3) * 4096 + lr * 256;                   \
        const bfrag _kh0 = *(const bfrag*)(_c + ((lg * 16) ^ swk));            \
        const bfrag _kh1 = *(const bfrag*)(_c + (((lg + 4) * 16) ^ swk));      \
        const bfrag _kl0 = *(const bfrag*)(_c + 128 + ((lg * 16) ^ swk));      \
        const bfrag _kl1 = *(const bfrag*)(_c + 128 + (((lg + 4) * 16) ^ swk));\
        int4 _mva, _mvb;                                                       \
        if constexpr (PRE) { _mva = MA; _mvb = MB; }                           \
        else {                                                                 \
            _mva = *(const int4*)(mr0 + (T) * 16);                             \
            _mvb = *(const int4*)(mr1 + (T) * 16);                             \
        }                                                                      \
        asm volatile("s_waitcnt lgkmcnt(0)" ::: "memory");                     \
        __builtin_amdgcn_sched_barrier(0);                                     \
        if constexpr ((T) + 3 < 16) {                                          \
            STAGE((T) + 3);                                                    \
            if constexpr (PRE) {                                               \
                if (DOPF) {                                                    \
                    MA = *(const int4*)(mr0 + ((T) + 3) * 16);                 \
                    MB = *(const int4*)(mr1 + ((T) + 3) * 16);                 \
                }                                                              \
            }                                                                  \
        }                                                                      \
        /* group 0: hh chain + mixed chain */                                  \
        f32x4 _h = {0.f, 0.f, 0.f, 0.f};                                       \
        f32x4 _m = {0.f, 0.f, 0.f, 0.f};                                       \
        _h = MF(_kh0, qh0a, _h);  _m = MF(_kh0, ql0a, _m);                     \
        _h = MF(_kh1, qh1a, _h);  _m = MF(_kl0, qh0a, _m);                     \
        _m = MF(_kh1, ql1a, _m);  _m = MF(_kl1, qh1a, _m);                     \
        const f32x4 _s0 = _h + _m;                                             \
        /* group 1 */                                                          \
        f32x4 _h2 = {0.f, 0.f, 0.f, 0.f};                                      \
        f32x4 _m2 = {0.f, 0.f, 0.f, 0.f};                                      \
        _h2 = MF(_kh0, qh0b, _h2);  _m2 = MF(_kh0, ql0b, _m2);                 \
        _h2 = MF(_kh1, qh1b, _h2);  _m2 = MF(_kl0, qh0b, _m2);                 \
        _m2 = MF(_kh1, ql1b, _m2);  _m2 = MF(_kl1, qh1b, _m2);                 \
        const f32x4 _s1 = _h2 + _m2;                                           \
        const unsigned _n0 = NIB4(_mva);                                       \
        const unsigned _n1 = NIB4(_mvb);                                       \
        const float _e0 = (_n0 & 1u) ? exp2f(_s0[0]) : 0.f;                    \
        const float _e1 = (_n0 & 2u) ? exp2f(_s0[1]) : 0.f;                    \
        const float _e2 = (_n0 & 4u) ? exp2f(_s0[2]) : 0.f;                    \
        const float _e3 = (_n0 & 8u) ? exp2f(_s0[3]) : 0.f;                    \
        const float _f0 = (_n1 & 1u) ? exp2f(_s1[0]) : 0.f;                    \
        const float _f1 = (_n1 & 2u) ? exp2f(_s1[1]) : 0.f;                    \
        const float _f2 = (_n1 & 4u) ? exp2f(_s1[2]) : 0.f;                    \
        const float _f3 = (_n1 & 8u) ? exp2f(_s1[3]) : 0.f;                    \
        psum0 += (_e0 + _e1) + (_e2 + _e3);                                    \
        psum1 += (_f0 + _f1) + (_f2 + _f3);                                    \
        asm volatile("v_cvt_pk_bf16_f32 %0, %1, %2"                            \
                     : "=v"(sc[4 * (T)])     : "v"(_e0), "v"(_e1));            \
        asm volatile("v_cvt_pk_bf16_f32 %0, %1, %2"                            \
                     : "=v"(sc[4 * (T) + 1]) : "v"(_e2), "v"(_e3));            \
        asm volatile("v_cvt_pk_bf16_f32 %0, %1, %2"                            \
                     : "=v"(sc[4 * (T) + 2]) : "v"(_f0), "v"(_f1));            \
        asm volatile("v_cvt_pk_bf16_f32 %0, %1, %2"                            \
                     : "=v"(sc[4 * (T) + 3]) : "v"(_f2), "v"(_f3));            \
    } while (0)

    // ledger: per-iter VMEM group = {4 k-gld16 + 2 mask-int4} (k first).
    // vmcnt(12) = exactly two newer groups outstanding -> group T complete.
    // Stages/prefetch stop after tile 15 (issued at T=12): tail 12, 6, 0.
    ITER(0,  12, mA0, mB0, 1); ITER(1,  12, mA1, mB1, 1);
    ITER(2,  12, mA2, mB2, 1); ITER(3,  12, mA0, mB0, 1);
    ITER(4,  12, mA1, mB1, 1); ITER(5,  12, mA2, mB2, 1);
    ITER(6,  12, mA0, mB0, 1); ITER(7,  12, mA1, mB1, 1);
    ITER(8,  12, mA2, mB2, 1); ITER(9,  12, mA0, mB0, 1);
    ITER(10, 12, mA1, mB1, 1); ITER(11, 12, mA2, mB2, 1);
    ITER(12, 12, mA0, mB0, 1); ITER(13, 12, mA1, mB1, 0);
    ITER(14, 6,  mA2, mB2, 0); ITER(15, 0,  mA0, mB0, 0);
#undef ITER
#undef STAGE

    // ---- row sums: lanes {l, l^16, l^32, l^48} share each q-row
    psum0 += __shfl_xor(psum0, 16, 64);
    psum0 += __shfl_xor(psum0, 32, 64);
    psum1 += __shfl_xor(psum1, 16, 64);
    psum1 += __shfl_xor(psum1, 32, 64);

    float* s_red = (float*)(pool + 8 * 12288);   // [wave][group][16]
    __syncthreads();
    if (l < 16) {
        s_red[w * 32 + lr]      = psum0;
        s_red[w * 32 + 16 + lr] = psum1;
    }
    __syncthreads();

    float tot0 = 0.f, tot1 = 0.f;
    #pragma unroll
    for (int ww = 0; ww < 8; ++ww) {
        tot0 += s_red[ww * 32 + lr];
        tot1 += s_red[ww * 32 + 16 + lr];
    }
    const float rinv0 = 1.0f / tot0;
    const float rinv1 = 1.0f / tot1;

    // ---- unpack, normalize, float4 stores (both row groups)
    float* op0 = out + row0 * SKL + c0 + lg * 4;
    float* op1 = out + row1 * SKL + c0 + lg * 4;
    #pragma unroll
    for (int T = 0; T < 16; ++T) {
        const unsigned pa = sc[4 * T], pb = sc[4 * T + 1];
        const unsigned pc = sc[4 * T + 2], pd = sc[4 * T + 3];
        f32x4 o0, o1;
        o0[0] = bf2f((unsigned short)(pa & 0xffffu)) * rinv0;
        o0[1] = bf2f((unsigned short)(pa >> 16))     * rinv0;
        o0[2] = bf2f((unsigned short)(pb & 0xffffu)) * rinv0;
        o0[3] = bf2f((unsigned short)(pb >> 16))     * rinv0;
        o1[0] = bf2f((unsigned short)(pc & 0xffffu)) * rinv1;
        o1[1] = bf2f((unsigned short)(pc >> 16))     * rinv1;
        o1[2] = bf2f((unsigned short)(pd & 0xffffu)) * rinv1;
        o1[3] = bf2f((unsigned short)(pd >> 16))     * rinv1;
        *reinterpret_cast<f32x4*>(op0 + T * 16) = o0;
        *reinterpret_cast<f32x4*>(op1 + T * 16) = o1;
    }
}

extern "C" void kernel_launch(void* const* d_in, const int* in_sizes, int n_in,
                              void* d_out, int out_size, void* d_ws, size_t ws_size,
                              hipStream_t stream) {
    const float* q    = (const float*)d_in[0];
    const float* k    = (const float*)d_in[1];
    const int*   mask = (const int*)d_in[2];
    float*       out  = (float*)d_out;

    const size_t KS_B = (size_t)BB * SKL * 256;       // 16.78 MB swizzled k

    dim3 grid(2048);    // 32 batches x 64 row-blocks, XCD-swizzled in-kernel

    if (ws_size >= KS_B) {
        unsigned char* ksp = (unsigned char*)d_ws;
        split_k_swz<<<2048, 256, 0, stream>>>(k, ksp);
        sdpa_v16<true><<<grid, 512, 0, stream>>>(q, k, mask, ksp, out);
    } else {
        sdpa_v16<false><<<grid, 512, 0, stream>>>(q, k, mask, nullptr, out);
    }
}